// Round 6
// baseline (579.186 us; speedup 1.0000x reference)
//
#include <hip/hip_runtime.h>
#include <hip/hip_bf16.h>

#define N_NODES 50000
#define N_EDGES 800000
#define IN_C 512
#define HID_C 256
#define OUT_C 128
#define SCAN_BLOCKS 49  // ceil(50000 / 1024)

typedef short bf16x8 __attribute__((ext_vector_type(8)));
typedef float f32x4 __attribute__((ext_vector_type(4)));

__device__ __forceinline__ float bf2f(unsigned short u) {
    return __uint_as_float(((unsigned)u) << 16);
}
__device__ __forceinline__ unsigned short f2bf(float f) {
    __hip_bfloat16 h = __float2bfloat16(f);
    return *(unsigned short*)&h;
}

// ---------------------------------------------------------------- CSR build
__global__ void zero_counts_kernel(int* __restrict__ counts) {
    int i = blockIdx.x * blockDim.x + threadIdx.x;
    if (i < N_NODES) counts[i] = 0;
}

__global__ void count_kernel(const int* __restrict__ ei, int* __restrict__ counts) {
    int e = blockIdx.x * blockDim.x + threadIdx.x;
    if (e < N_EDGES) atomicAdd(&counts[ei[N_EDGES + e]], 1);
}

__global__ __launch_bounds__(256) void scan_part_kernel(const int* __restrict__ counts,
                                                        int* __restrict__ excl,
                                                        int* __restrict__ bsums) {
    __shared__ int tsum[256];
    const int t = threadIdx.x;
    const int base = blockIdx.x * 1024 + t * 4;
    int v[4];
    int s = 0;
#pragma unroll
    for (int j = 0; j < 4; j++) {
        int idx = base + j;
        v[j] = (idx < N_NODES) ? counts[idx] : 0;
        s += v[j];
    }
    tsum[t] = s;
    __syncthreads();
    for (int off = 1; off < 256; off <<= 1) {
        int add = (t >= off) ? tsum[t - off] : 0;
        __syncthreads();
        tsum[t] += add;
        __syncthreads();
    }
    int run = tsum[t] - s;
#pragma unroll
    for (int j = 0; j < 4; j++) {
        int idx = base + j;
        if (idx < N_NODES) excl[idx] = run;
        run += v[j];
    }
    if (t == 255) bsums[blockIdx.x] = tsum[255];
}

// wave-parallel exclusive scan of the 49 block sums
__global__ void scan_sums_kernel(int* __restrict__ bsums) {
    int ln = threadIdx.x;  // 64 threads = 1 wave
    int v = (ln < SCAN_BLOCKS) ? bsums[ln] : 0;
    for (int off = 1; off < 64; off <<= 1) {
        int u = __shfl_up(v, off, 64);
        if (ln >= off) v += u;
    }
    int excl = __shfl_up(v, 1, 64);
    if (ln == 0) excl = 0;
    if (ln < SCAN_BLOCKS) bsums[ln] = excl;
}

__global__ void add_dinv_kernel(int* __restrict__ offsets, const int* __restrict__ bsums,
                                int* __restrict__ woff, const int* __restrict__ counts,
                                float* __restrict__ dinv) {
    int i = blockIdx.x * blockDim.x + threadIdx.x;
    if (i < N_NODES) {
        int o = offsets[i] + bsums[i >> 10];
        offsets[i] = o;
        woff[i] = o;
        dinv[i] = rsqrtf(1.0f + (float)counts[i]);
    }
    if (i == 0) offsets[N_NODES] = N_EDGES;
}

__global__ void fill_kernel(const int* __restrict__ ei, int* __restrict__ woff,
                            int* __restrict__ sorted_src) {
    int e = blockIdx.x * blockDim.x + threadIdx.x;
    if (e < N_EDGES) {
        int s = ei[e];
        int d = ei[N_EDGES + e];
        int pos = atomicAdd(&woff[d], 1);
        sorted_src[pos] = s;
    }
}

// ---------------------------------------------------------------- casts
__global__ __launch_bounds__(256) void cast_x_kernel(const float* __restrict__ x,
                                                     unsigned short* __restrict__ xb) {
    size_t i = ((size_t)blockIdx.x * 256 + threadIdx.x) * 4;  // grid sized exactly
    float4 v = *(const float4*)&x[i];
    ushort4 o;
    o.x = f2bf(v.x); o.y = f2bf(v.y); o.z = f2bf(v.z); o.w = f2bf(v.w);
    *(ushort4*)&xb[i] = o;
}

// WT[n][k] = bf16(W[k][n]); grid covers N*K exactly
__global__ __launch_bounds__(256) void tcast_kernel(const float* __restrict__ W,
                                                    unsigned short* __restrict__ WT,
                                                    int K, int N) {
    int idx = blockIdx.x * 256 + threadIdx.x;
    int n = idx / K, k = idx - n * K;
    WT[idx] = f2bf(W[(size_t)k * N + n]);
}

// ---------------------------------------------------------------- MFMA GEMM
// C[M,N](bf16) = A[M,K](bf16) @ BT[N,K](bf16)^T. 128x128 block tile, BK=32,
// 256 threads = 4 waves, each wave a 64x64 quadrant via 4x4 of 16x16x32 MFMA.
__global__ __launch_bounds__(256) void mfma_gemm_bt(const unsigned short* __restrict__ A,
                                                    const unsigned short* __restrict__ BT,
                                                    unsigned short* __restrict__ C,
                                                    int M, int N, int K) {
    __shared__ unsigned short As[128 * 32];  // [row][k] 64B rows
    __shared__ unsigned short Bs[128 * 32];

    const int tid = threadIdx.x;
    const int w = tid >> 6;
    const int ln = tid & 63;
    const int br = blockIdx.y * 128;
    const int bc = blockIdx.x * 128;

    const int quad = ln >> 4;
    const int l16 = ln & 15;
    const int wr = (w >> 1) * 64;
    const int wc = (w & 1) * 64;

    const int crow = ln >> 2;
    const int koff = (ln & 3) * 8;

    f32x4 acc[4][4];
#pragma unroll
    for (int mt = 0; mt < 4; mt++)
#pragma unroll
        for (int nt = 0; nt < 4; nt++) acc[mt][nt] = (f32x4){0.f, 0.f, 0.f, 0.f};

    for (int kk = 0; kk < K; kk += 32) {
#pragma unroll
        for (int t = 0; t < 2; t++) {
            int c = w + t * 4;
            int row = br + c * 16 + crow;
            row = row < M ? row : M - 1;  // clamp (dup read, stores guarded)
            const unsigned short* gp = A + (size_t)row * K + kk + koff;
            unsigned short* lp = As + c * 512 + ln * 8;
            __builtin_amdgcn_global_load_lds((const __attribute__((address_space(1))) void*)gp,
                                             (__attribute__((address_space(3))) void*)lp,
                                             16, 0, 0);
        }
#pragma unroll
        for (int t = 0; t < 2; t++) {
            int c = w + t * 4;
            int row = bc + c * 16 + crow;
            const unsigned short* gp = BT + (size_t)row * K + kk + koff;
            unsigned short* lp = Bs + c * 512 + ln * 8;
            __builtin_amdgcn_global_load_lds((const __attribute__((address_space(1))) void*)gp,
                                             (__attribute__((address_space(3))) void*)lp,
                                             16, 0, 0);
        }
        __syncthreads();

        bf16x8 af[4], bfr[4];
#pragma unroll
        for (int mt = 0; mt < 4; mt++)
            af[mt] = *(const bf16x8*)&As[(wr + mt * 16 + l16) * 32 + quad * 8];
#pragma unroll
        for (int nt = 0; nt < 4; nt++)
            bfr[nt] = *(const bf16x8*)&Bs[(wc + nt * 16 + l16) * 32 + quad * 8];
#pragma unroll
        for (int mt = 0; mt < 4; mt++)
#pragma unroll
            for (int nt = 0; nt < 4; nt++)
                acc[mt][nt] = __builtin_amdgcn_mfma_f32_16x16x32_bf16(af[mt], bfr[nt],
                                                                      acc[mt][nt], 0, 0, 0);
        __syncthreads();
    }

#pragma unroll
    for (int mt = 0; mt < 4; mt++) {
#pragma unroll
        for (int r = 0; r < 4; r++) {
            int gr = br + wr + mt * 16 + quad * 4 + r;
            if (gr < M) {
#pragma unroll
                for (int nt = 0; nt < 4; nt++) {
                    int gc = bc + wc + nt * 16 + l16;
                    C[(size_t)gr * N + gc] = f2bf(acc[mt][nt][r]);
                }
            }
        }
    }
}

// ------------------------------------------------- sliced gather aggregation
// Channel-sliced for L2 residency: slice = 32 ch (64 B). slice = blockIdx.x %
// NS, so with round-robin block->XCD dispatch each slice's H-columns (3.2 MB)
// stay resident in ONE XCD's 4 MB L2 -> gather reads become L2 hits.
// Wave layout: 16 groups x 4 lanes x 16 B = one row-slice per edge; 16 edge
// substreams per node; butterfly-reduce across groups. Block = 4 waves, each
// wave processes 4 nodes serially (block covers 16 nodes).
// out[i,c] = relu?( dinv[i]^2*H[i,c] + b[c] + sum_e dinv[i]*dinv[src]*H[src,c] )
template <int C, bool RELU, bool BF16_OUT>
__global__ __launch_bounds__(256) void gather_slice_kernel(
    const int* __restrict__ offsets, const int* __restrict__ ssrc,
    const unsigned short* __restrict__ H, const float* __restrict__ dinv,
    const float* __restrict__ bias, void* __restrict__ outv) {
    constexpr int NS = C / 32;  // 8 (C=256) or 4 (C=128)
    const int slice = blockIdx.x % NS;
    const int chunk = blockIdx.x / NS;
    const int w = threadIdx.x >> 6;
    const int ln = threadIdx.x & 63;
    const int g = ln >> 2;   // group 0..15 (edge substream)
    const int l = ln & 3;    // lane within group
    const int c0 = slice * 32 + l * 8;

    float bv[8];
    {
        float4 b0 = *(const float4*)&bias[c0];
        float4 b1 = *(const float4*)&bias[c0 + 4];
        bv[0] = b0.x; bv[1] = b0.y; bv[2] = b0.z; bv[3] = b0.w;
        bv[4] = b1.x; bv[5] = b1.y; bv[6] = b1.z; bv[7] = b1.w;
    }

#pragma unroll
    for (int t = 0; t < 4; t++) {
        const int node = chunk * 16 + w * 4 + t;
        if (node >= N_NODES) return;
        const float di = dinv[node];

        float acc[8] = {};
        if (g == 0) {  // self term + bias exactly once per channel
            bf16x8 h = *(const bf16x8*)&H[(size_t)node * C + c0];
#pragma unroll
            for (int j = 0; j < 8; j++)
                acc[j] = di * di * bf2f((unsigned short)h[j]) + bv[j];
        }

        int k = offsets[node] + g;
        const int k1 = offsets[node + 1];
        for (; k < k1; k += 16) {
            int s = ssrc[k];
            float wgt = di * dinv[s];
            bf16x8 h = *(const bf16x8*)&H[(size_t)s * C + c0];
#pragma unroll
            for (int j = 0; j < 8; j++) acc[j] += wgt * bf2f((unsigned short)h[j]);
        }

        // butterfly across the 16 groups (strides 4,8,16,32 lanes)
#pragma unroll
        for (int m = 4; m < 64; m <<= 1) {
#pragma unroll
            for (int j = 0; j < 8; j++) acc[j] += __shfl_xor(acc[j], m, 64);
        }

        if (g == 0) {
            if (RELU) {
#pragma unroll
                for (int j = 0; j < 8; j++) acc[j] = fmaxf(acc[j], 0.0f);
            }
            if (BF16_OUT) {
                bf16x8 o;
#pragma unroll
                for (int j = 0; j < 8; j++) o[j] = (short)f2bf(acc[j]);
                *(bf16x8*)&((unsigned short*)outv)[(size_t)node * C + c0] = o;
            } else {
                float* out = (float*)outv;
                *(float4*)&out[(size_t)node * C + c0] = make_float4(acc[0], acc[1], acc[2], acc[3]);
                *(float4*)&out[(size_t)node * C + c0 + 4] = make_float4(acc[4], acc[5], acc[6], acc[7]);
            }
        }
    }
}

// ---------------------------------------------------------------- launcher
extern "C" void kernel_launch(void* const* d_in, const int* in_sizes, int n_in,
                              void* d_out, int out_size, void* d_ws, size_t ws_size,
                              hipStream_t stream) {
    const float* x  = (const float*)d_in[0];
    const int*   ei = (const int*)d_in[1];
    const float* W1 = (const float*)d_in[2];
    const float* b1 = (const float*)d_in[3];
    const float* W2 = (const float*)d_in[4];
    const float* b2 = (const float*)d_in[5];
    float* out = (float*)d_out;

    // workspace layout (4-byte words). Total ~20.3M words = 81 MiB
    // (< known-good 98 MiB; R2's 101.5 MiB overflowed and corrupted inputs).
    int*   counts     = (int*)d_ws;                          // 50048
    int*   offsets    = counts + 50048;                      // 50052 (+sentinel)
    int*   woff       = offsets + 50052;                     // 50048
    int*   bsums      = woff + 50048;                        // 64
    float* dinv       = (float*)(bsums + 64);                // 50048
    int*   sorted_src = (int*)(dinv + 50048);                // 800000
    unsigned short* W1T = (unsigned short*)(sorted_src + 800000);     // 131072 sh
    unsigned short* W2T = W1T + 131072;                               // 32768 sh
    unsigned short* xb  = W2T + 32768;                                // 25.6M sh
    unsigned short* H1  = xb + (size_t)N_NODES * IN_C;                // 12.8M sh
    unsigned short* A1b = xb;                                         // overlay
    unsigned short* H2  = xb + (size_t)N_NODES * HID_C;               // overlay

    // CSR build + norm
    zero_counts_kernel<<<(N_NODES + 255) / 256, 256, 0, stream>>>(counts);
    count_kernel<<<(N_EDGES + 255) / 256, 256, 0, stream>>>(ei, counts);
    scan_part_kernel<<<SCAN_BLOCKS, 256, 0, stream>>>(counts, offsets, bsums);
    scan_sums_kernel<<<1, 64, 0, stream>>>(bsums);
    add_dinv_kernel<<<(N_NODES + 255) / 256, 256, 0, stream>>>(offsets, bsums, woff, counts, dinv);
    fill_kernel<<<(N_EDGES + 255) / 256, 256, 0, stream>>>(ei, woff, sorted_src);

    // bf16 casts
    cast_x_kernel<<<(N_NODES * IN_C) / 1024, 256, 0, stream>>>(x, xb);
    tcast_kernel<<<(IN_C * HID_C) / 256, 256, 0, stream>>>(W1, W1T, IN_C, HID_C);
    tcast_kernel<<<(HID_C * OUT_C) / 256, 256, 0, stream>>>(W2, W2T, HID_C, OUT_C);

    // layer 1: H1 = xb @ W1T^T  (bf16 MFMA)
    {
        dim3 grid(HID_C / 128, (N_NODES + 127) / 128);
        mfma_gemm_bt<<<grid, 256, 0, stream>>>(xb, W1T, H1, N_NODES, HID_C, IN_C);
    }
    // gather1: 8 slices x 3125 node-chunks (16 nodes/block)
    gather_slice_kernel<HID_C, true, true><<<8 * 3125, 256, 0, stream>>>(
        offsets, sorted_src, H1, dinv, b1, (void*)A1b);

    // layer 2: H2 = A1b @ W2T^T  (relu already applied in gather1 output)
    {
        dim3 grid(OUT_C / 128, (N_NODES + 127) / 128);
        mfma_gemm_bt<<<grid, 256, 0, stream>>>(A1b, W2T, H2, N_NODES, OUT_C, HID_C);
    }
    // gather2: 4 slices x 3125 node-chunks
    gather_slice_kernel<OUT_C, false, false><<<4 * 3125, 256, 0, stream>>>(
        offsets, sorted_src, H2, dinv, b2, (void*)out);
}